// Round 2
// baseline (1273.134 us; speedup 1.0000x reference)
//
#include <hip/hip_runtime.h>
#include <math.h>

#define N_NODES 10000
#define KE 31
#define SD 8
#define ID 2
#define ZD 32
#define ED 64
#define HH 128
#define FC 128
#define AT 16
#define FT 6
#define DT_C 0.25f
#define NT 32

__device__ __forceinline__ float sigm(float x){ return 1.0f/(1.0f+__expf(-x)); }
__device__ __forceinline__ float tanh_f(float x){ return 1.0f - 2.0f/(1.0f+__expf(2.0f*x)); }

// ---------------- init: oh/oc/sh/sc = s0 @ W + b ; u = 0 ----------------
__global__ __launch_bounds__(256) void init_kernel(
    const float* __restrict__ s0,
    const float* __restrict__ oh0_W, const float* __restrict__ oh0_b,
    const float* __restrict__ oc0_W, const float* __restrict__ oc0_b,
    const float* __restrict__ sh0_W, const float* __restrict__ sh0_b,
    const float* __restrict__ sc0_W, const float* __restrict__ sc0_b,
    float* __restrict__ oh, float* __restrict__ oc,
    float* __restrict__ sh, float* __restrict__ sc, float* __restrict__ u)
{
  int t = blockIdx.x*256 + threadIdx.x;
  if (t < N_NODES*ID) u[t] = 0.0f;
  if (t >= N_NODES*HH) return;
  int n = t >> 7, j = t & 127;
  float s[SD];
  #pragma unroll
  for (int i=0;i<SD;i++) s[i] = s0[n*SD+i];
  float a0=oh0_b[j], a1=oc0_b[j], a2=sh0_b[j], a3=sc0_b[j];
  #pragma unroll
  for (int i=0;i<SD;i++){
    a0 = fmaf(s[i], oh0_W[i*HH+j], a0);
    a1 = fmaf(s[i], oc0_W[i*HH+j], a1);
    a2 = fmaf(s[i], sh0_W[i*HH+j], a2);
    a3 = fmaf(s[i], sc0_W[i*HH+j], a3);
  }
  oh[t]=a0; oc[t]=a1; sh[t]=a2; sc[t]=a3;
}

// ---------------- K1: edge encode + attention -> ctx [N, ED] ----------------
// one wave per node; 4 nodes per 256-thread block; grid = N/4 = 2500 exactly
__global__ __launch_bounds__(256) void edge_att(
    const float* __restrict__ s_prev, const float* __restrict__ s0,
    const int* __restrict__ edge_idx1, const int* __restrict__ edge_idx2,
    const int* __restrict__ node_obs_idx,
    const float* __restrict__ W_edge, const float* __restrict__ b_edge,
    const float* __restrict__ att_W1, const float* __restrict__ att_W2,
    const float* __restrict__ att_v, float* __restrict__ ctx)
{
  __shared__ float enc_s[4][KE][65];   // stride 65 -> conflict-free rows & cols
  const int tid  = threadIdx.x;
  const int w    = tid >> 6;
  const int lane = tid & 63;
  const int n    = blockIdx.x*4 + w;   // grid covers N exactly

  // per-lane W_edge columns
  float WcA[SD], WcB[SD];
  #pragma unroll
  for (int i=0;i<SD;i++){ WcA[i] = W_edge[i*ED + lane]; WcB[i] = W_edge[(SD+i)*ED + lane]; }
  const float be = b_edge[lane];

  // rel and rel @ att_W2 (redundant per lane; tiny)
  float rel[SD];
  #pragma unroll
  for (int i=0;i<SD;i++) rel[i] = s_prev[n*SD+i] - s0[n*SD+i];
  float rW2[AT];
  #pragma unroll
  for (int a=0;a<AT;a++){
    float acc = 0.f;
    #pragma unroll
    for (int i=0;i<SD;i++) acc = fmaf(rel[i], att_W2[i*AT+a], acc);
    rW2[a] = acc;
  }

  // phase A: encode K edges, lane owns enc dim
  for (int k=0;k<KE;k++){
    int idx = node_obs_idx[n*KE + k];
    float v = 0.f;
    if (idx > 0){
      int e  = idx - 1;
      int i1 = edge_idx1[e];
      int i2 = edge_idx2[e];
      v = be;
      #pragma unroll
      for (int i=0;i<SD;i++) v = fmaf(s_prev[i1*SD+i], WcA[i], v);
      #pragma unroll
      for (int i=0;i<SD;i++) v = fmaf(s_prev[i2*SD+i], WcB[i], v);
      v = fmaxf(v, 0.f);
    }
    enc_s[w][k][lane] = v;
  }
  __syncthreads();

  // phase B: lane k (<31) computes its score; att_W1 reads are wave-uniform -> s_load
  float score = -INFINITY;
  if (lane < KE){
    float t16[AT];
    #pragma unroll
    for (int a=0;a<AT;a++) t16[a] = rW2[a];
    for (int d=0; d<ED; ++d){
      float ev = enc_s[w][lane][d];
      #pragma unroll
      for (int a=0;a<AT;a++) t16[a] = fmaf(ev, att_W1[d*AT+a], t16[a]);
    }
    float sc_ = 0.f;
    #pragma unroll
    for (int a=0;a<AT;a++) sc_ = fmaf(att_v[a], tanh_f(t16[a]), sc_);
    score = sc_;
  }

  // phase C: softmax over lanes (31 real, rest -inf)
  float m = score;
  #pragma unroll
  for (int off=32; off; off>>=1) m = fmaxf(m, __shfl_xor(m, off));
  float p = (lane < KE) ? __expf(score - m) : 0.f;
  float ssum = p;
  #pragma unroll
  for (int off=32; off; off>>=1) ssum += __shfl_xor(ssum, off);
  float alpha = p / ssum;

  // phase D: ctx[d] = sum_k alpha_k * enc[k][d]
  float cacc = 0.f;
  for (int k=0;k<KE;k++){
    float ak = __shfl(alpha, k);
    cacc = fmaf(ak, enc_s[w][k][lane], cacc);
  }
  ctx[n*ED + lane] = cacc;
}

// ---------------- K2: LSTMs + action net + dynamics ----------------
// 256 threads, NT=32 nodes/block; thread (h, node-half) owns all 4 gate cols
__global__ __launch_bounds__(256) void node_update(
    const float* __restrict__ s_prev, const float* __restrict__ s0,
    const float* __restrict__ z, const float* __restrict__ ctx,
    const float* __restrict__ obs_Wi, const float* __restrict__ obs_Wh, const float* __restrict__ obs_b,
    const float* __restrict__ st_Wi, const float* __restrict__ st_Wh, const float* __restrict__ st_b,
    const float* __restrict__ act_W1, const float* __restrict__ act_b1,
    const float* __restrict__ act_W2, const float* __restrict__ act_b2,
    const float* __restrict__ dyn_A, const float* __restrict__ dyn_B,
    float* __restrict__ oh, float* __restrict__ oc,
    float* __restrict__ sh, float* __restrict__ sc,
    float* __restrict__ u, float* __restrict__ s_next,
    float* __restrict__ out_state, float* __restrict__ out_input, int tstep)
{
  __shared__ float A_act[NT][SD+HH+HH+ZD];      // 32 x 296 action-net input
  __shared__ union {
    float X1[NT][ED+HH];                        // obs-LSTM input (192)
    float X2[NT][SD+ID+HH+2];                   // st-LSTM input (138, pad 140)
    float F [NT][FC+1];                         // relu hidden (stride 129: conflict-free)
  } ubuf;
  __shared__ float u2s[NT][ID];
  __shared__ float sps[NT][SD];

  const int tid = threadIdx.x;
  const int n0  = blockIdx.x * NT;

  // ---- loads ----
  for (int idx=tid; idx<NT*SD; idx+=256){
    int n=idx>>3, i=idx&7; int gn=n0+n;
    if (gn<N_NODES){ float sv=s_prev[gn*SD+i]; A_act[n][i]=sv - s0[gn*SD+i]; sps[n][i]=sv; }
  }
  for (int idx=tid; idx<NT*ZD; idx+=256){
    int n=idx>>5, i=idx&31; int gn=n0+n;
    if (gn<N_NODES) A_act[n][SD+HH+HH+i] = z[gn*ZD+i];
  }
  for (int idx=tid; idx<NT*ED; idx+=256){
    int n=idx>>6, i=idx&63; int gn=n0+n;
    if (gn<N_NODES) ubuf.X1[n][i] = ctx[gn*ED+i];
  }
  for (int idx=tid; idx<NT*HH; idx+=256){
    int n=idx>>7, i=idx&127; int gn=n0+n;
    if (gn<N_NODES) ubuf.X1[n][ED+i] = oh[gn*HH+i];
  }
  __syncthreads();

  const int h  = tid & 127;
  const int nh = (tid >> 7) << 4;     // node half base 0/16

  // ---- obs LSTM ----
  {
    float ai[16], af[16], ag[16], ao[16];
    #pragma unroll
    for (int r=0;r<16;r++){ ai[r]=0.f; af[r]=0.f; ag[r]=0.f; ao[r]=0.f; }
    for (int i=0;i<ED;++i){
      float wi_ = obs_Wi[i*4*HH + h];
      float wf_ = obs_Wi[i*4*HH + HH + h];
      float wg_ = obs_Wi[i*4*HH + 2*HH + h];
      float wo_ = obs_Wi[i*4*HH + 3*HH + h];
      #pragma unroll
      for (int r=0;r<16;r++){
        float x = ubuf.X1[nh+r][i];
        ai[r]=fmaf(wi_,x,ai[r]); af[r]=fmaf(wf_,x,af[r]);
        ag[r]=fmaf(wg_,x,ag[r]); ao[r]=fmaf(wo_,x,ao[r]);
      }
    }
    for (int i=0;i<HH;++i){
      float wi_ = obs_Wh[i*4*HH + h];
      float wf_ = obs_Wh[i*4*HH + HH + h];
      float wg_ = obs_Wh[i*4*HH + 2*HH + h];
      float wo_ = obs_Wh[i*4*HH + 3*HH + h];
      #pragma unroll
      for (int r=0;r<16;r++){
        float x = ubuf.X1[nh+r][ED+i];
        ai[r]=fmaf(wi_,x,ai[r]); af[r]=fmaf(wf_,x,af[r]);
        ag[r]=fmaf(wg_,x,ag[r]); ao[r]=fmaf(wo_,x,ao[r]);
      }
    }
    #pragma unroll
    for (int r=0;r<16;r++){
      int n = nh + r; int gn = n0 + n;
      if (gn < N_NODES){
        float gi = ai[r] + obs_b[h];
        float gf = af[r] + obs_b[HH+h];
        float gg = ag[r] + obs_b[2*HH+h];
        float go = ao[r] + obs_b[3*HH+h];
        float cold = oc[gn*HH+h];
        float c2 = sigm(gf)*cold + sigm(gi)*tanh_f(gg);
        float h2 = sigm(go)*tanh_f(c2);
        oc[gn*HH+h] = c2;
        oh[gn*HH+h] = h2;
        A_act[n][SD+h] = h2;
      }
    }
  }
  __syncthreads();

  // ---- st LSTM input loads ----
  for (int idx=tid; idx<NT*HH; idx+=256){
    int n=idx>>7, i=idx&127; int gn=n0+n;
    if (gn<N_NODES) ubuf.X2[n][SD+ID+i] = sh[gn*HH+i];
  }
  for (int idx=tid; idx<NT*(SD+ID); idx+=256){
    int n=idx/(SD+ID), i=idx%(SD+ID); int gn=n0+n;
    if (gn<N_NODES) ubuf.X2[n][i] = (i<SD) ? A_act[n][i] : u[gn*ID + (i-SD)];
  }
  __syncthreads();

  // ---- st LSTM ----
  {
    float ai[16], af[16], ag[16], ao[16];
    #pragma unroll
    for (int r=0;r<16;r++){ ai[r]=0.f; af[r]=0.f; ag[r]=0.f; ao[r]=0.f; }
    for (int i=0;i<SD+ID;++i){
      float wi_ = st_Wi[i*4*HH + h];
      float wf_ = st_Wi[i*4*HH + HH + h];
      float wg_ = st_Wi[i*4*HH + 2*HH + h];
      float wo_ = st_Wi[i*4*HH + 3*HH + h];
      #pragma unroll
      for (int r=0;r<16;r++){
        float x = ubuf.X2[nh+r][i];
        ai[r]=fmaf(wi_,x,ai[r]); af[r]=fmaf(wf_,x,af[r]);
        ag[r]=fmaf(wg_,x,ag[r]); ao[r]=fmaf(wo_,x,ao[r]);
      }
    }
    for (int i=0;i<HH;++i){
      float wi_ = st_Wh[i*4*HH + h];
      float wf_ = st_Wh[i*4*HH + HH + h];
      float wg_ = st_Wh[i*4*HH + 2*HH + h];
      float wo_ = st_Wh[i*4*HH + 3*HH + h];
      #pragma unroll
      for (int r=0;r<16;r++){
        float x = ubuf.X2[nh+r][SD+ID+i];
        ai[r]=fmaf(wi_,x,ai[r]); af[r]=fmaf(wf_,x,af[r]);
        ag[r]=fmaf(wg_,x,ag[r]); ao[r]=fmaf(wo_,x,ao[r]);
      }
    }
    #pragma unroll
    for (int r=0;r<16;r++){
      int n = nh + r; int gn = n0 + n;
      if (gn < N_NODES){
        float gi = ai[r] + st_b[h];
        float gf = af[r] + st_b[HH+h];
        float gg = ag[r] + st_b[2*HH+h];
        float go = ao[r] + st_b[3*HH+h];
        float cold = sc[gn*HH+h];
        float c2 = sigm(gf)*cold + sigm(gi)*tanh_f(gg);
        float h2 = sigm(go)*tanh_f(c2);
        sc[gn*HH+h] = c2;
        sh[gn*HH+h] = h2;
        A_act[n][SD+HH+h] = h2;
      }
    }
  }
  __syncthreads();

  // ---- action net layer 1 ----
  {
    float acc[16];
    #pragma unroll
    for (int r=0;r<16;r++) acc[r]=0.f;
    for (int i=0;i<SD+HH+HH+ZD;++i){
      float wv = act_W1[i*FC + h];
      #pragma unroll
      for (int r=0;r<16;r++) acc[r] = fmaf(wv, A_act[nh+r][i], acc[r]);
    }
    float b1 = act_b1[h];
    #pragma unroll
    for (int r=0;r<16;r++) ubuf.F[nh+r][h] = fmaxf(acc[r] + b1, 0.f);
  }
  __syncthreads();

  // ---- action net layer 2 -> u2 ----
  if (tid < NT*ID){
    int n = tid >> 1, c = tid & 1; int gn = n0 + n;
    float acc = act_b2[c];
    for (int j=0;j<FC;++j) acc = fmaf(ubuf.F[n][j], act_W2[j*ID+c], acc);
    u2s[n][c] = acc;
    if (gn < N_NODES){
      u[gn*ID+c] = acc;
      out_input[tstep*N_NODES*ID + gn*ID + c] = acc;
    }
  }
  __syncthreads();

  // ---- dynamics ----
  if (tid < NT*SD){
    int n = tid >> 3, d = tid & 7; int gn = n0 + n;
    if (gn < N_NODES){
      float acc = 0.f;
      #pragma unroll
      for (int e=0;e<SD;++e) acc = fmaf(sps[n][e], dyn_A[d*SD+e], acc);
      #pragma unroll
      for (int c=0;c<ID;++c) acc = fmaf(u2s[n][c], dyn_B[d*ID+c], acc);
      float s2v = sps[n][d] + DT_C*acc;
      s_next[gn*SD+d] = s2v;
      out_state[tstep*N_NODES*SD + gn*SD + d] = s2v;
    }
  }
}

extern "C" void kernel_launch(void* const* d_in, const int* in_sizes, int n_in,
                              void* d_out, int out_size, void* d_ws, size_t ws_size,
                              hipStream_t stream)
{
  const float* state_history = (const float*)d_in[0];
  const float* z        = (const float*)d_in[1];
  const int*   edge_idx1 = (const int*)d_in[2];
  const int*   edge_idx2 = (const int*)d_in[3];
  const int*   node_obs_idx = (const int*)d_in[4];
  const float* W_edge  = (const float*)d_in[5];
  const float* b_edge  = (const float*)d_in[6];
  const float* att_W1  = (const float*)d_in[7];
  const float* att_W2  = (const float*)d_in[8];
  const float* att_v   = (const float*)d_in[9];
  const float* obs_Wi  = (const float*)d_in[10];
  const float* obs_Wh  = (const float*)d_in[11];
  const float* obs_b   = (const float*)d_in[12];
  const float* st_Wi   = (const float*)d_in[13];
  const float* st_Wh   = (const float*)d_in[14];
  const float* st_b    = (const float*)d_in[15];
  const float* oh0_W   = (const float*)d_in[16];
  const float* oh0_b   = (const float*)d_in[17];
  const float* oc0_W   = (const float*)d_in[18];
  const float* oc0_b   = (const float*)d_in[19];
  const float* sh0_W   = (const float*)d_in[20];
  const float* sh0_b   = (const float*)d_in[21];
  const float* sc0_W   = (const float*)d_in[22];
  const float* sc0_b   = (const float*)d_in[23];
  const float* act_W1  = (const float*)d_in[24];
  const float* act_b1  = (const float*)d_in[25];
  const float* act_W2  = (const float*)d_in[26];
  const float* act_b2  = (const float*)d_in[27];
  const float* dyn_A   = (const float*)d_in[28];
  const float* dyn_B   = (const float*)d_in[29];

  const float* s0 = state_history + 3*N_NODES*SD;

  float* wsf = (float*)d_ws;
  float* sbuf0 = wsf;
  float* sbuf1 = sbuf0 + N_NODES*SD;
  float* oh  = sbuf1 + N_NODES*SD;
  float* oc  = oh + N_NODES*HH;
  float* sh  = oc + N_NODES*HH;
  float* sc  = sh + N_NODES*HH;
  float* u   = sc + N_NODES*HH;
  float* ctx = u  + N_NODES*ID;
  float* sbuf[2] = { sbuf0, sbuf1 };

  float* out_state = (float*)d_out;
  float* out_input = out_state + FT*N_NODES*SD;

  hipLaunchKernelGGL(init_kernel, dim3((N_NODES*HH+255)/256), dim3(256), 0, stream,
      s0, oh0_W, oh0_b, oc0_W, oc0_b, sh0_W, sh0_b, sc0_W, sc0_b, oh, oc, sh, sc, u);

  for (int t = 0; t < FT; ++t){
    const float* s_prev = (t==0) ? s0 : sbuf[(t-1)&1];
    float* s_next = sbuf[t&1];
    hipLaunchKernelGGL(edge_att, dim3(N_NODES/4), dim3(256), 0, stream,
        s_prev, s0, edge_idx1, edge_idx2, node_obs_idx,
        W_edge, b_edge, att_W1, att_W2, att_v, ctx);
    hipLaunchKernelGGL(node_update, dim3((N_NODES+NT-1)/NT), dim3(256), 0, stream,
        s_prev, s0, z, ctx,
        obs_Wi, obs_Wh, obs_b, st_Wi, st_Wh, st_b,
        act_W1, act_b1, act_W2, act_b2, dyn_A, dyn_B,
        oh, oc, sh, sc, u, s_next, out_state, out_input, t);
  }
}

// Round 5
// 1047.593 us; speedup vs baseline: 1.2153x; 1.2153x over previous
//
#include <hip/hip_runtime.h>
#include <math.h>

#define N_NODES 10000
#define KE 31
#define SD 8
#define ID 2
#define ZD 32
#define ED 64
#define HH 128
#define FC 128
#define AT 16
#define FT 6
#define DT_C 0.25f
#define NT 8   // nodes per node_update block (was 32): grid 1250, LDS ~16KB -> ~5 blocks/CU

__device__ __forceinline__ float sigm(float x){ return 1.0f/(1.0f+__expf(-x)); }
__device__ __forceinline__ float tanh_f(float x){ return 1.0f - 2.0f/(1.0f+__expf(2.0f*x)); }

// ---------------- init: oh/oc/sh/sc = s0 @ W + b ; u = 0 ----------------
__global__ __launch_bounds__(256) void init_kernel(
    const float* __restrict__ s0,
    const float* __restrict__ oh0_W, const float* __restrict__ oh0_b,
    const float* __restrict__ oc0_W, const float* __restrict__ oc0_b,
    const float* __restrict__ sh0_W, const float* __restrict__ sh0_b,
    const float* __restrict__ sc0_W, const float* __restrict__ sc0_b,
    float* __restrict__ oh, float* __restrict__ oc,
    float* __restrict__ sh, float* __restrict__ sc, float* __restrict__ u)
{
  int t = blockIdx.x*256 + threadIdx.x;
  if (t < N_NODES*ID) u[t] = 0.0f;
  if (t >= N_NODES*HH) return;
  int n = t >> 7, j = t & 127;
  float s[SD];
  #pragma unroll
  for (int i=0;i<SD;i++) s[i] = s0[n*SD+i];
  float a0=oh0_b[j], a1=oc0_b[j], a2=sh0_b[j], a3=sc0_b[j];
  #pragma unroll
  for (int i=0;i<SD;i++){
    a0 = fmaf(s[i], oh0_W[i*HH+j], a0);
    a1 = fmaf(s[i], oc0_W[i*HH+j], a1);
    a2 = fmaf(s[i], sh0_W[i*HH+j], a2);
    a3 = fmaf(s[i], sc0_W[i*HH+j], a3);
  }
  oh[t]=a0; oc[t]=a1; sh[t]=a2; sc[t]=a3;
}

// ---------------- K1: edge encode + attention -> ctx [N, ED] ----------------
// one wave per node; 4 nodes per 256-thread block; grid = N/4 = 2500 exactly
__global__ __launch_bounds__(256) void edge_att(
    const float* __restrict__ s_prev, const float* __restrict__ s0,
    const int* __restrict__ edge_idx1, const int* __restrict__ edge_idx2,
    const int* __restrict__ node_obs_idx,
    const float* __restrict__ W_edge, const float* __restrict__ b_edge,
    const float* __restrict__ att_W1, const float* __restrict__ att_W2,
    const float* __restrict__ att_v, float* __restrict__ ctx)
{
  __shared__ float enc_s[4][KE][65];   // stride 65 -> conflict-free rows & cols
  const int tid  = threadIdx.x;
  const int w    = tid >> 6;
  const int lane = tid & 63;
  const int n    = blockIdx.x*4 + w;   // grid covers N exactly

  // per-lane W_edge columns
  float WcA[SD], WcB[SD];
  #pragma unroll
  for (int i=0;i<SD;i++){ WcA[i] = W_edge[i*ED + lane]; WcB[i] = W_edge[(SD+i)*ED + lane]; }
  const float be = b_edge[lane];

  // rel and rel @ att_W2 (redundant per lane; tiny)
  float rel[SD];
  #pragma unroll
  for (int i=0;i<SD;i++) rel[i] = s_prev[n*SD+i] - s0[n*SD+i];
  float rW2[AT];
  #pragma unroll
  for (int a=0;a<AT;a++){
    float acc = 0.f;
    #pragma unroll
    for (int i=0;i<SD;i++) acc = fmaf(rel[i], att_W2[i*AT+a], acc);
    rW2[a] = acc;
  }

  // phase A: encode K edges, lane owns enc dim
  for (int k=0;k<KE;k++){
    int idx = node_obs_idx[n*KE + k];
    float v = 0.f;
    if (idx > 0){
      int e  = idx - 1;
      int i1 = edge_idx1[e];
      int i2 = edge_idx2[e];
      v = be;
      #pragma unroll
      for (int i=0;i<SD;i++) v = fmaf(s_prev[i1*SD+i], WcA[i], v);
      #pragma unroll
      for (int i=0;i<SD;i++) v = fmaf(s_prev[i2*SD+i], WcB[i], v);
      v = fmaxf(v, 0.f);
    }
    enc_s[w][k][lane] = v;
  }
  __syncthreads();

  // phase B: lane k (<31) computes its score; att_W1 reads are wave-uniform -> s_load
  float score = -INFINITY;
  if (lane < KE){
    float t16[AT];
    #pragma unroll
    for (int a=0;a<AT;a++) t16[a] = rW2[a];
    for (int d=0; d<ED; ++d){
      float ev = enc_s[w][lane][d];
      #pragma unroll
      for (int a=0;a<AT;a++) t16[a] = fmaf(ev, att_W1[d*AT+a], t16[a]);
    }
    float sc_ = 0.f;
    #pragma unroll
    for (int a=0;a<AT;a++) sc_ = fmaf(att_v[a], tanh_f(t16[a]), sc_);
    score = sc_;
  }

  // phase C: softmax over lanes (31 real, rest -inf)
  float m = score;
  #pragma unroll
  for (int off=32; off; off>>=1) m = fmaxf(m, __shfl_xor(m, off));
  float p = (lane < KE) ? __expf(score - m) : 0.f;
  float ssum = p;
  #pragma unroll
  for (int off=32; off; off>>=1) ssum += __shfl_xor(ssum, off);
  float alpha = p / ssum;

  // phase D: ctx[d] = sum_k alpha_k * enc[k][d]
  float cacc = 0.f;
  for (int k=0;k<KE;k++){
    float ak = __shfl(alpha, k);
    cacc = fmaf(ak, enc_s[w][k][lane], cacc);
  }
  ctx[n*ED + lane] = cacc;
}

// ---------------- K2: LSTMs + action net + dynamics ----------------
// 256 threads, NT=8 nodes/block; thread (h, node-half) owns all 4 gate cols
// for its half's 4 nodes. grid = 1250 -> ~5 blocks/CU (was 313 @ 1 block/CU).
__global__ __launch_bounds__(256) void node_update(
    const float* __restrict__ s_prev, const float* __restrict__ s0,
    const float* __restrict__ z, const float* __restrict__ ctx,
    const float* __restrict__ obs_Wi, const float* __restrict__ obs_Wh, const float* __restrict__ obs_b,
    const float* __restrict__ st_Wi, const float* __restrict__ st_Wh, const float* __restrict__ st_b,
    const float* __restrict__ act_W1, const float* __restrict__ act_b1,
    const float* __restrict__ act_W2, const float* __restrict__ act_b2,
    const float* __restrict__ dyn_A, const float* __restrict__ dyn_B,
    float* __restrict__ oh, float* __restrict__ oc,
    float* __restrict__ sh, float* __restrict__ sc,
    float* __restrict__ u, float* __restrict__ s_next,
    float* __restrict__ out_state, float* __restrict__ out_input, int tstep)
{
  __shared__ float A_act[NT][SD+HH+HH+ZD];      // 8 x 296 action-net input
  __shared__ union {
    float X1[NT][ED+HH];                        // obs-LSTM input (192)
    float X2[NT][SD+ID+HH+2];                   // st-LSTM input (138, pad 140)
    float F [NT][FC+1];                         // relu hidden (stride 129: conflict-free)
  } ubuf;
  __shared__ float u2s[NT][ID];
  __shared__ float sps[NT][SD];

  const int tid = threadIdx.x;
  const int n0  = blockIdx.x * NT;

  // ---- loads ----
  for (int idx=tid; idx<NT*SD; idx+=256){
    int n=idx>>3, i=idx&7; int gn=n0+n;
    if (gn<N_NODES){ float sv=s_prev[gn*SD+i]; A_act[n][i]=sv - s0[gn*SD+i]; sps[n][i]=sv; }
  }
  for (int idx=tid; idx<NT*ZD; idx+=256){
    int n=idx>>5, i=idx&31; int gn=n0+n;
    if (gn<N_NODES) A_act[n][SD+HH+HH+i] = z[gn*ZD+i];
  }
  for (int idx=tid; idx<NT*ED; idx+=256){
    int n=idx>>6, i=idx&63; int gn=n0+n;
    if (gn<N_NODES) ubuf.X1[n][i] = ctx[gn*ED+i];
  }
  for (int idx=tid; idx<NT*HH; idx+=256){
    int n=idx>>7, i=idx&127; int gn=n0+n;
    if (gn<N_NODES) ubuf.X1[n][ED+i] = oh[gn*HH+i];
  }
  __syncthreads();

  const int h  = tid & 127;
  const int nh = (tid >> 7) << 2;     // node base 0/4 per half

  // ---- obs LSTM ----
  {
    float ai[4], af[4], ag[4], ao[4];
    #pragma unroll
    for (int r=0;r<4;r++){ ai[r]=0.f; af[r]=0.f; ag[r]=0.f; ao[r]=0.f; }
    for (int i=0;i<ED;++i){
      float wi_ = obs_Wi[i*4*HH + h];
      float wf_ = obs_Wi[i*4*HH + HH + h];
      float wg_ = obs_Wi[i*4*HH + 2*HH + h];
      float wo_ = obs_Wi[i*4*HH + 3*HH + h];
      #pragma unroll
      for (int r=0;r<4;r++){
        float x = ubuf.X1[nh+r][i];
        ai[r]=fmaf(wi_,x,ai[r]); af[r]=fmaf(wf_,x,af[r]);
        ag[r]=fmaf(wg_,x,ag[r]); ao[r]=fmaf(wo_,x,ao[r]);
      }
    }
    for (int i=0;i<HH;++i){
      float wi_ = obs_Wh[i*4*HH + h];
      float wf_ = obs_Wh[i*4*HH + HH + h];
      float wg_ = obs_Wh[i*4*HH + 2*HH + h];
      float wo_ = obs_Wh[i*4*HH + 3*HH + h];
      #pragma unroll
      for (int r=0;r<4;r++){
        float x = ubuf.X1[nh+r][ED+i];
        ai[r]=fmaf(wi_,x,ai[r]); af[r]=fmaf(wf_,x,af[r]);
        ag[r]=fmaf(wg_,x,ag[r]); ao[r]=fmaf(wo_,x,ao[r]);
      }
    }
    #pragma unroll
    for (int r=0;r<4;r++){
      int n = nh + r; int gn = n0 + n;
      if (gn < N_NODES){
        float gi = ai[r] + obs_b[h];
        float gf = af[r] + obs_b[HH+h];
        float gg = ag[r] + obs_b[2*HH+h];
        float go = ao[r] + obs_b[3*HH+h];
        float cold = oc[gn*HH+h];
        float c2 = sigm(gf)*cold + sigm(gi)*tanh_f(gg);
        float h2 = sigm(go)*tanh_f(c2);
        oc[gn*HH+h] = c2;
        oh[gn*HH+h] = h2;
        A_act[n][SD+h] = h2;
      }
    }
  }
  __syncthreads();

  // ---- st LSTM input loads ----
  for (int idx=tid; idx<NT*HH; idx+=256){
    int n=idx>>7, i=idx&127; int gn=n0+n;
    if (gn<N_NODES) ubuf.X2[n][SD+ID+i] = sh[gn*HH+i];
  }
  for (int idx=tid; idx<NT*(SD+ID); idx+=256){
    int n=idx/(SD+ID), i=idx%(SD+ID); int gn=n0+n;
    if (gn<N_NODES) ubuf.X2[n][i] = (i<SD) ? A_act[n][i] : u[gn*ID + (i-SD)];
  }
  __syncthreads();

  // ---- st LSTM ----
  {
    float ai[4], af[4], ag[4], ao[4];
    #pragma unroll
    for (int r=0;r<4;r++){ ai[r]=0.f; af[r]=0.f; ag[r]=0.f; ao[r]=0.f; }
    for (int i=0;i<SD+ID;++i){
      float wi_ = st_Wi[i*4*HH + h];
      float wf_ = st_Wi[i*4*HH + HH + h];
      float wg_ = st_Wi[i*4*HH + 2*HH + h];
      float wo_ = st_Wi[i*4*HH + 3*HH + h];
      #pragma unroll
      for (int r=0;r<4;r++){
        float x = ubuf.X2[nh+r][i];
        ai[r]=fmaf(wi_,x,ai[r]); af[r]=fmaf(wf_,x,af[r]);
        ag[r]=fmaf(wg_,x,ag[r]); ao[r]=fmaf(wo_,x,ao[r]);
      }
    }
    for (int i=0;i<HH;++i){
      float wi_ = st_Wh[i*4*HH + h];
      float wf_ = st_Wh[i*4*HH + HH + h];
      float wg_ = st_Wh[i*4*HH + 2*HH + h];
      float wo_ = st_Wh[i*4*HH + 3*HH + h];
      #pragma unroll
      for (int r=0;r<4;r++){
        float x = ubuf.X2[nh+r][SD+ID+i];
        ai[r]=fmaf(wi_,x,ai[r]); af[r]=fmaf(wf_,x,af[r]);
        ag[r]=fmaf(wg_,x,ag[r]); ao[r]=fmaf(wo_,x,ao[r]);
      }
    }
    #pragma unroll
    for (int r=0;r<4;r++){
      int n = nh + r; int gn = n0 + n;
      if (gn < N_NODES){
        float gi = ai[r] + st_b[h];
        float gf = af[r] + st_b[HH+h];
        float gg = ag[r] + st_b[2*HH+h];
        float go = ao[r] + st_b[3*HH+h];
        float cold = sc[gn*HH+h];
        float c2 = sigm(gf)*cold + sigm(gi)*tanh_f(gg);
        float h2 = sigm(go)*tanh_f(c2);
        sc[gn*HH+h] = c2;
        sh[gn*HH+h] = h2;
        A_act[n][SD+HH+h] = h2;
      }
    }
  }
  __syncthreads();

  // ---- action net layer 1 ----
  {
    float acc[4];
    #pragma unroll
    for (int r=0;r<4;r++) acc[r]=0.f;
    for (int i=0;i<SD+HH+HH+ZD;++i){
      float wv = act_W1[i*FC + h];
      #pragma unroll
      for (int r=0;r<4;r++) acc[r] = fmaf(wv, A_act[nh+r][i], acc[r]);
    }
    float b1 = act_b1[h];
    #pragma unroll
    for (int r=0;r<4;r++) ubuf.F[nh+r][h] = fmaxf(acc[r] + b1, 0.f);
  }
  __syncthreads();

  // ---- action net layer 2 -> u2 ----
  if (tid < NT*ID){
    int n = tid >> 1, c = tid & 1; int gn = n0 + n;
    float acc = act_b2[c];
    for (int j=0;j<FC;++j) acc = fmaf(ubuf.F[n][j], act_W2[j*ID+c], acc);
    u2s[n][c] = acc;
    if (gn < N_NODES){
      u[gn*ID+c] = acc;
      out_input[tstep*N_NODES*ID + gn*ID + c] = acc;
    }
  }
  __syncthreads();

  // ---- dynamics ----
  if (tid < NT*SD){
    int n = tid >> 3, d = tid & 7; int gn = n0 + n;
    if (gn < N_NODES){
      float acc = 0.f;
      #pragma unroll
      for (int e=0;e<SD;++e) acc = fmaf(sps[n][e], dyn_A[d*SD+e], acc);
      #pragma unroll
      for (int c=0;c<ID;++c) acc = fmaf(u2s[n][c], dyn_B[d*ID+c], acc);
      float s2v = sps[n][d] + DT_C*acc;
      s_next[gn*SD+d] = s2v;
      out_state[tstep*N_NODES*SD + gn*SD + d] = s2v;
    }
  }
}

extern "C" void kernel_launch(void* const* d_in, const int* in_sizes, int n_in,
                              void* d_out, int out_size, void* d_ws, size_t ws_size,
                              hipStream_t stream)
{
  const float* state_history = (const float*)d_in[0];
  const float* z        = (const float*)d_in[1];
  const int*   edge_idx1 = (const int*)d_in[2];
  const int*   edge_idx2 = (const int*)d_in[3];
  const int*   node_obs_idx = (const int*)d_in[4];
  const float* W_edge  = (const float*)d_in[5];
  const float* b_edge  = (const float*)d_in[6];
  const float* att_W1  = (const float*)d_in[7];
  const float* att_W2  = (const float*)d_in[8];
  const float* att_v   = (const float*)d_in[9];
  const float* obs_Wi  = (const float*)d_in[10];
  const float* obs_Wh  = (const float*)d_in[11];
  const float* obs_b   = (const float*)d_in[12];
  const float* st_Wi   = (const float*)d_in[13];
  const float* st_Wh   = (const float*)d_in[14];
  const float* st_b    = (const float*)d_in[15];
  const float* oh0_W   = (const float*)d_in[16];
  const float* oh0_b   = (const float*)d_in[17];
  const float* oc0_W   = (const float*)d_in[18];
  const float* oc0_b   = (const float*)d_in[19];
  const float* sh0_W   = (const float*)d_in[20];
  const float* sh0_b   = (const float*)d_in[21];
  const float* sc0_W   = (const float*)d_in[22];
  const float* sc0_b   = (const float*)d_in[23];
  const float* act_W1  = (const float*)d_in[24];
  const float* act_b1  = (const float*)d_in[25];
  const float* act_W2  = (const float*)d_in[26];
  const float* act_b2  = (const float*)d_in[27];
  const float* dyn_A   = (const float*)d_in[28];
  const float* dyn_B   = (const float*)d_in[29];

  const float* s0 = state_history + 3*N_NODES*SD;

  float* wsf = (float*)d_ws;
  float* sbuf0 = wsf;
  float* sbuf1 = sbuf0 + N_NODES*SD;
  float* oh  = sbuf1 + N_NODES*SD;
  float* oc  = oh + N_NODES*HH;
  float* sh  = oc + N_NODES*HH;
  float* sc  = sh + N_NODES*HH;
  float* u   = sc + N_NODES*HH;
  float* ctx = u  + N_NODES*ID;
  float* sbuf[2] = { sbuf0, sbuf1 };

  float* out_state = (float*)d_out;
  float* out_input = out_state + FT*N_NODES*SD;

  hipLaunchKernelGGL(init_kernel, dim3((N_NODES*HH+255)/256), dim3(256), 0, stream,
      s0, oh0_W, oh0_b, oc0_W, oc0_b, sh0_W, sh0_b, sc0_W, sc0_b, oh, oc, sh, sc, u);

  for (int t = 0; t < FT; ++t){
    const float* s_prev = (t==0) ? s0 : sbuf[(t-1)&1];
    float* s_next = sbuf[t&1];
    hipLaunchKernelGGL(edge_att, dim3(N_NODES/4), dim3(256), 0, stream,
        s_prev, s0, edge_idx1, edge_idx2, node_obs_idx,
        W_edge, b_edge, att_W1, att_W2, att_v, ctx);
    hipLaunchKernelGGL(node_update, dim3((N_NODES+NT-1)/NT), dim3(256), 0, stream,
        s_prev, s0, z, ctx,
        obs_Wi, obs_Wh, obs_b, st_Wi, st_Wh, st_b,
        act_W1, act_b1, act_W2, act_b2, dyn_A, dyn_B,
        oh, oc, sh, sc, u, s_next, out_state, out_input, t);
  }
}

// Round 6
// 718.762 us; speedup vs baseline: 1.7713x; 1.4575x over previous
//
#include <hip/hip_runtime.h>
#include <hip/hip_bf16.h>
#include <math.h>

#define N_NODES 10000
#define KE 31
#define SD 8
#define ID 2
#define ZD 32
#define ED 64
#define HH 128
#define FC 128
#define AT 16
#define FT 6
#define DT_C 0.25f
#define NT 16          // nodes per node_update block: grid = 625 exactly (16*625=10000)

#define NKS_O 6        // obs LSTM K=192 = 6*32
#define NKS_S 5        // st LSTM  K=160 = 5*32 (138 real + zero pad)
#define NKS_A 10       // act1     K=320 = 10*32 (296 real + zero pad)

typedef __bf16 bf16x8 __attribute__((ext_vector_type(8)));
typedef float  f32x4  __attribute__((ext_vector_type(4)));

__device__ __forceinline__ float sigm(float x){ return 1.0f/(1.0f+__expf(-x)); }
__device__ __forceinline__ float tanh_f(float x){ return 1.0f - 2.0f/(1.0f+__expf(2.0f*x)); }

__device__ __forceinline__ unsigned short f2b(float f){
  __hip_bfloat16 h = __float2bfloat16(f);
  return __builtin_bit_cast(unsigned short, h);
}
__device__ __forceinline__ unsigned int pack2(float a, float b){
  return (unsigned int)f2b(a) | ((unsigned int)f2b(b) << 16);
}
__device__ __forceinline__ bf16x8 as_bf16x8(int4 v){
  union { int4 i; bf16x8 b; } u; u.i = v; return u.b;
}

// ---------------- pack_weights: fp32 W -> bf16 B-fragment order in ws ----------------
// B-frag map (16x16x32): col = ctile*16 + (lane&15); k = ks*32 + (lane>>4)*8 + j, j=0..7
// packed as uint (2 bf16) at [((ctile*NKS + ks)*64 + lane)*4 + j/2]
__global__ __launch_bounds__(256) void pack_weights(
    const float* __restrict__ obs_Wi, const float* __restrict__ obs_Wh,
    const float* __restrict__ st_Wi,  const float* __restrict__ st_Wh,
    const float* __restrict__ act_W1,
    unsigned int* __restrict__ wp_obs, unsigned int* __restrict__ wp_st,
    unsigned int* __restrict__ wp_act)
{
  int t = blockIdx.x*256 + threadIdx.x;
  if (t < 49152){                       // obs: 32 ctiles * 6 ks * 256 uints
    int c = t / 1536; int r = t - c*1536;
    int ks = r >> 8; int q = r & 255;
    int ln = q >> 2; int dw = q & 3;
    int k  = ks*32 + ((ln>>4)<<3) + dw*2;
    int col = (c<<4) + (ln & 15);
    float v0 = (k   < 64) ? obs_Wi[k*4*HH + col]      : obs_Wh[(k-64)*4*HH + col];
    float v1 = (k+1 < 64) ? obs_Wi[(k+1)*4*HH + col]  : obs_Wh[(k-63)*4*HH + col];
    wp_obs[t] = pack2(v0, v1);
  } else if (t < 90112){                // st: 32 ctiles * 5 ks * 256
    int t2 = t - 49152;
    int c = t2 / 1280; int r = t2 - c*1280;
    int ks = r >> 8; int q = r & 255;
    int ln = q >> 2; int dw = q & 3;
    int k  = ks*32 + ((ln>>4)<<3) + dw*2;
    int col = (c<<4) + (ln & 15);
    float v0, v1;
    { int kk=k;   v0 = (kk<10)? st_Wi[kk*4*HH+col] : (kk<138 ? st_Wh[(kk-10)*4*HH+col] : 0.f); }
    { int kk=k+1; v1 = (kk<10)? st_Wi[kk*4*HH+col] : (kk<138 ? st_Wh[(kk-10)*4*HH+col] : 0.f); }
    wp_st[t2] = pack2(v0, v1);
  } else if (t < 110592){               // act1: 8 ctiles * 10 ks * 256
    int t3 = t - 90112;
    int c = t3 / 2560; int r = t3 - c*2560;
    int ks = r >> 8; int q = r & 255;
    int ln = q >> 2; int dw = q & 3;
    int k  = ks*32 + ((ln>>4)<<3) + dw*2;
    int col = (c<<4) + (ln & 15);
    float v0 = (k   < 296) ? act_W1[k*FC + col]     : 0.f;
    float v1 = (k+1 < 296) ? act_W1[(k+1)*FC + col] : 0.f;
    wp_act[t3] = pack2(v0, v1);
  }
}

// ---------------- init: oh/oc/sh/sc = s0 @ W + b ; u = 0 ----------------
__global__ __launch_bounds__(256) void init_kernel(
    const float* __restrict__ s0,
    const float* __restrict__ oh0_W, const float* __restrict__ oh0_b,
    const float* __restrict__ oc0_W, const float* __restrict__ oc0_b,
    const float* __restrict__ sh0_W, const float* __restrict__ sh0_b,
    const float* __restrict__ sc0_W, const float* __restrict__ sc0_b,
    float* __restrict__ oh, float* __restrict__ oc,
    float* __restrict__ sh, float* __restrict__ sc, float* __restrict__ u)
{
  int t = blockIdx.x*256 + threadIdx.x;
  if (t < N_NODES*ID) u[t] = 0.0f;
  if (t >= N_NODES*HH) return;
  int n = t >> 7, j = t & 127;
  float s[SD];
  #pragma unroll
  for (int i=0;i<SD;i++) s[i] = s0[n*SD+i];
  float a0=oh0_b[j], a1=oc0_b[j], a2=sh0_b[j], a3=sc0_b[j];
  #pragma unroll
  for (int i=0;i<SD;i++){
    a0 = fmaf(s[i], oh0_W[i*HH+j], a0);
    a1 = fmaf(s[i], oc0_W[i*HH+j], a1);
    a2 = fmaf(s[i], sh0_W[i*HH+j], a2);
    a3 = fmaf(s[i], sc0_W[i*HH+j], a3);
  }
  oh[t]=a0; oc[t]=a1; sh[t]=a2; sc[t]=a3;
}

// ---------------- K1: edge encode + attention -> ctx [N, ED] (unchanged) ----------------
__global__ __launch_bounds__(256) void edge_att(
    const float* __restrict__ s_prev, const float* __restrict__ s0,
    const int* __restrict__ edge_idx1, const int* __restrict__ edge_idx2,
    const int* __restrict__ node_obs_idx,
    const float* __restrict__ W_edge, const float* __restrict__ b_edge,
    const float* __restrict__ att_W1, const float* __restrict__ att_W2,
    const float* __restrict__ att_v, float* __restrict__ ctx)
{
  __shared__ float enc_s[4][KE][65];
  const int tid  = threadIdx.x;
  const int w    = tid >> 6;
  const int lane = tid & 63;
  const int n    = blockIdx.x*4 + w;

  float WcA[SD], WcB[SD];
  #pragma unroll
  for (int i=0;i<SD;i++){ WcA[i] = W_edge[i*ED + lane]; WcB[i] = W_edge[(SD+i)*ED + lane]; }
  const float be = b_edge[lane];

  float rel[SD];
  #pragma unroll
  for (int i=0;i<SD;i++) rel[i] = s_prev[n*SD+i] - s0[n*SD+i];
  float rW2[AT];
  #pragma unroll
  for (int a=0;a<AT;a++){
    float acc = 0.f;
    #pragma unroll
    for (int i=0;i<SD;i++) acc = fmaf(rel[i], att_W2[i*AT+a], acc);
    rW2[a] = acc;
  }

  for (int k=0;k<KE;k++){
    int idx = node_obs_idx[n*KE + k];
    float v = 0.f;
    if (idx > 0){
      int e  = idx - 1;
      int i1 = edge_idx1[e];
      int i2 = edge_idx2[e];
      v = be;
      #pragma unroll
      for (int i=0;i<SD;i++) v = fmaf(s_prev[i1*SD+i], WcA[i], v);
      #pragma unroll
      for (int i=0;i<SD;i++) v = fmaf(s_prev[i2*SD+i], WcB[i], v);
      v = fmaxf(v, 0.f);
    }
    enc_s[w][k][lane] = v;
  }
  __syncthreads();

  float score = -INFINITY;
  if (lane < KE){
    float t16[AT];
    #pragma unroll
    for (int a=0;a<AT;a++) t16[a] = rW2[a];
    for (int d=0; d<ED; ++d){
      float ev = enc_s[w][lane][d];
      #pragma unroll
      for (int a=0;a<AT;a++) t16[a] = fmaf(ev, att_W1[d*AT+a], t16[a]);
    }
    float sc_ = 0.f;
    #pragma unroll
    for (int a=0;a<AT;a++) sc_ = fmaf(att_v[a], tanh_f(t16[a]), sc_);
    score = sc_;
  }

  float m = score;
  #pragma unroll
  for (int off=32; off; off>>=1) m = fmaxf(m, __shfl_xor(m, off));
  float p = (lane < KE) ? __expf(score - m) : 0.f;
  float ssum = p;
  #pragma unroll
  for (int off=32; off; off>>=1) ssum += __shfl_xor(ssum, off);
  float alpha = p / ssum;

  float cacc = 0.f;
  for (int k=0;k<KE;k++){
    float ak = __shfl(alpha, k);
    cacc = fmaf(ak, enc_s[w][k][lane], cacc);
  }
  ctx[n*ED + lane] = cacc;
}

// ---------------- K2: MFMA LSTMs + action net + dynamics ----------------
// 256 threads = 4 waves; NT=16 nodes (one 16-row M tile); wave w owns h in [w*32, w*32+32).
// A-frag map: row m = lane&15, k = ks*32 + (lane>>4)*8 + j  (same k-convention as B pack,
// so any within-lane k permutation in HW cancels between A and B).
// C/D map (HW-verified): col = lane&15, row = (lane>>4)*4 + reg.
__global__ __launch_bounds__(256) void node_update_mfma(
    const float* __restrict__ s_prev, const float* __restrict__ s0,
    const float* __restrict__ z, const float* __restrict__ ctx,
    const unsigned int* __restrict__ wp_obs, const unsigned int* __restrict__ wp_st,
    const unsigned int* __restrict__ wp_act,
    const float* __restrict__ obs_b, const float* __restrict__ st_b,
    const float* __restrict__ act_b1,
    const float* __restrict__ act_W2, const float* __restrict__ act_b2,
    const float* __restrict__ dyn_A, const float* __restrict__ dyn_B,
    float* __restrict__ oh, float* __restrict__ oc,
    float* __restrict__ sh, float* __restrict__ sc,
    float* __restrict__ u, float* __restrict__ s_next,
    float* __restrict__ out_state, float* __restrict__ out_input, int tstep)
{
  __shared__ __align__(16) unsigned int fragX1[NKS_O*64*4];  // X1=[ctx|oh]      K=192
  __shared__ __align__(16) unsigned int fragX2[NKS_S*64*4];  // X2=[rel|u|sh|0]  K=160
  __shared__ __align__(16) unsigned int fragX3[NKS_A*64*4];  // X3=[rel|oh2|sh2|z|0] K=320
  __shared__ float F[NT][FC+4];      // act1 relu output
  __shared__ float sps[NT][SD];
  __shared__ float u2p[NT][ID][8];
  __shared__ float u2s[NT][ID];

  const int tid  = threadIdx.x;
  const int n0   = blockIdx.x * NT;
  const int w    = tid >> 6;
  const int lane = tid & 63;

  // ---- phase 1: stage X fragments (bf16, A-frag order) ----
  // X1: 16 m x 96 k-pairs
  for (int idx = tid; idx < 16*96; idx += 256){
    int m = idx / 96, kp = idx - m*96; int k0 = kp*2; int gn = n0 + m;
    float v0, v1;
    if (k0 < ED){ v0 = ctx[gn*ED + k0]; v1 = ctx[gn*ED + k0 + 1]; }
    else        { v0 = oh[gn*HH + k0 - ED]; v1 = oh[gn*HH + k0 - ED + 1]; }
    int ln = m | (((k0>>3)&3)<<4);
    fragX1[(((k0>>5)*64 + ln)<<2) + ((k0&7)>>1)] = pack2(v0, v1);
  }
  // X2: 16 m x 80 k-pairs  (k<8 rel, 8..9 u, 10..137 sh, rest 0)
  for (int idx = tid; idx < 16*80; idx += 256){
    int m = idx / 80, kp = idx - m*80; int k0 = kp*2; int gn = n0 + m;
    float v0, v1;
    {
      int k = k0;
      v0 = (k<8) ? (s_prev[gn*SD+k]-s0[gn*SD+k]) : (k<10 ? u[gn*ID + k-8] : (k<138 ? sh[gn*HH + k-10] : 0.f));
      k = k0+1;
      v1 = (k<8) ? (s_prev[gn*SD+k]-s0[gn*SD+k]) : (k<10 ? u[gn*ID + k-8] : (k<138 ? sh[gn*HH + k-10] : 0.f));
    }
    int ln = m | (((k0>>3)&3)<<4);
    fragX2[(((k0>>5)*64 + ln)<<2) + ((k0&7)>>1)] = pack2(v0, v1);
  }
  // X3 partial: rel (k 0..7), z (k 264..295), zero pad (k 296..319); oh2/sh2 filled later
  for (int idx = tid; idx < 16*32; idx += 256){
    int m = idx / 32, p = idx - m*32; int gn = n0 + m;
    int k0 = (p < 4) ? p*2 : 256 + p*2;
    float v0, v1;
    if (k0 < 8){ v0 = s_prev[gn*SD+k0]-s0[gn*SD+k0]; v1 = s_prev[gn*SD+k0+1]-s0[gn*SD+k0+1]; }
    else if (k0 < 296){ v0 = z[gn*ZD + k0-264]; v1 = z[gn*ZD + k0-263]; }
    else { v0 = 0.f; v1 = 0.f; }
    int ln = m | (((k0>>3)&3)<<4);
    fragX3[(((k0>>5)*64 + ln)<<2) + ((k0&7)>>1)] = pack2(v0, v1);
  }
  if (tid < NT*SD){
    int m = tid >> 3, i = tid & 7;
    sps[m][i] = s_prev[(n0+m)*SD + i];
  }
  __syncthreads();

  // ---- obs LSTM: [16 x 192] @ [192 x 512], wave w cols = {g*128 + w*32 + t*16 + c} ----
  #pragma unroll
  for (int t = 0; t < 2; ++t){
    const int hcol = w*32 + t*16 + (lane & 15);
    f32x4 acc[4];
    #pragma unroll
    for (int g = 0; g < 4; ++g){
      float b = obs_b[g*HH + hcol];
      acc[g] = (f32x4){b, b, b, b};
    }
    for (int ks = 0; ks < NKS_O; ++ks){
      bf16x8 a = as_bf16x8(*(const int4*)&fragX1[((ks*64 + lane)<<2)]);
      #pragma unroll
      for (int g = 0; g < 4; ++g){
        int c = g*8 + w*2 + t;
        bf16x8 b = as_bf16x8(*(const int4*)&wp_obs[(((c*NKS_O + ks)*64 + lane)<<2)]);
        acc[g] = __builtin_amdgcn_mfma_f32_16x16x32_bf16(a, b, acc[g], 0, 0, 0);
      }
    }
    #pragma unroll
    for (int r = 0; r < 4; ++r){
      int m = ((lane>>4)<<2) + r; int gn = n0 + m;
      float gi = acc[0][r], gf = acc[1][r], gg = acc[2][r], go = acc[3][r];
      float cold = oc[gn*HH + hcol];
      float c2 = sigm(gf)*cold + sigm(gi)*tanh_f(gg);
      float h2 = sigm(go)*tanh_f(c2);
      oc[gn*HH + hcol] = c2;
      oh[gn*HH + hcol] = h2;
      int k = 8 + hcol;                      // X3 row for oh2
      int ln = m | (((k>>3)&3)<<4);
      ((unsigned short*)fragX3)[(((k>>5)*64 + ln)<<3) + (k&7)] = f2b(h2);
    }
  }

  // ---- st LSTM: [16 x 160] @ [160 x 512] ----
  #pragma unroll
  for (int t = 0; t < 2; ++t){
    const int hcol = w*32 + t*16 + (lane & 15);
    f32x4 acc[4];
    #pragma unroll
    for (int g = 0; g < 4; ++g){
      float b = st_b[g*HH + hcol];
      acc[g] = (f32x4){b, b, b, b};
    }
    for (int ks = 0; ks < NKS_S; ++ks){
      bf16x8 a = as_bf16x8(*(const int4*)&fragX2[((ks*64 + lane)<<2)]);
      #pragma unroll
      for (int g = 0; g < 4; ++g){
        int c = g*8 + w*2 + t;
        bf16x8 b = as_bf16x8(*(const int4*)&wp_st[(((c*NKS_S + ks)*64 + lane)<<2)]);
        acc[g] = __builtin_amdgcn_mfma_f32_16x16x32_bf16(a, b, acc[g], 0, 0, 0);
      }
    }
    #pragma unroll
    for (int r = 0; r < 4; ++r){
      int m = ((lane>>4)<<2) + r; int gn = n0 + m;
      float gi = acc[0][r], gf = acc[1][r], gg = acc[2][r], go = acc[3][r];
      float cold = sc[gn*HH + hcol];
      float c2 = sigm(gf)*cold + sigm(gi)*tanh_f(gg);
      float h2 = sigm(go)*tanh_f(c2);
      sc[gn*HH + hcol] = c2;
      sh[gn*HH + hcol] = h2;
      int k = 136 + hcol;                    // X3 row for sh2
      int ln = m | (((k>>3)&3)<<4);
      ((unsigned short*)fragX3)[(((k>>5)*64 + ln)<<3) + (k&7)] = f2b(h2);
    }
  }
  __syncthreads();   // X3 complete

  // ---- act1: [16 x 320] @ [320 x 128], wave w cols = [w*32, w*32+32) ----
  #pragma unroll
  for (int t = 0; t < 2; ++t){
    const int col = w*32 + t*16 + (lane & 15);
    float b = act_b1[col];
    f32x4 acc = (f32x4){b, b, b, b};
    for (int ks = 0; ks < NKS_A; ++ks){
      bf16x8 a = as_bf16x8(*(const int4*)&fragX3[((ks*64 + lane)<<2)]);
      int c = w*2 + t;
      bf16x8 bb = as_bf16x8(*(const int4*)&wp_act[(((c*NKS_A + ks)*64 + lane)<<2)]);
      acc = __builtin_amdgcn_mfma_f32_16x16x32_bf16(a, bb, acc, 0, 0, 0);
    }
    #pragma unroll
    for (int r = 0; r < 4; ++r){
      int m = ((lane>>4)<<2) + r;
      F[m][col] = fmaxf(acc[r], 0.f);
    }
  }
  __syncthreads();

  // ---- act2: u2 = relu_out @ act_W2 + b2 (VALU, tiny) ----
  {
    int m  = tid >> 4;
    int c  = (tid >> 3) & 1;
    int kq = tid & 7;
    float p = 0.f;
    #pragma unroll
    for (int i = 0; i < 16; ++i){
      int j = kq*16 + i;
      p = fmaf(F[m][j], act_W2[j*ID + c], p);
    }
    u2p[m][c][kq] = p;
  }
  __syncthreads();
  if (tid < NT*ID){
    int m = tid >> 1, c = tid & 1; int gn = n0 + m;
    float s = act_b2[c];
    #pragma unroll
    for (int kq = 0; kq < 8; ++kq) s += u2p[m][c][kq];
    u2s[m][c] = s;
    u[gn*ID + c] = s;
    out_input[tstep*N_NODES*ID + gn*ID + c] = s;
  }
  __syncthreads();

  // ---- dynamics ----
  if (tid < NT*SD){
    int m = tid >> 3, d = tid & 7; int gn = n0 + m;
    float acc = 0.f;
    #pragma unroll
    for (int e = 0; e < SD; ++e) acc = fmaf(sps[m][e], dyn_A[d*SD+e], acc);
    #pragma unroll
    for (int c = 0; c < ID; ++c) acc = fmaf(u2s[m][c], dyn_B[d*ID+c], acc);
    float s2v = sps[m][d] + DT_C*acc;
    s_next[gn*SD+d] = s2v;
    out_state[tstep*N_NODES*SD + gn*SD + d] = s2v;
  }
}

extern "C" void kernel_launch(void* const* d_in, const int* in_sizes, int n_in,
                              void* d_out, int out_size, void* d_ws, size_t ws_size,
                              hipStream_t stream)
{
  const float* state_history = (const float*)d_in[0];
  const float* z        = (const float*)d_in[1];
  const int*   edge_idx1 = (const int*)d_in[2];
  const int*   edge_idx2 = (const int*)d_in[3];
  const int*   node_obs_idx = (const int*)d_in[4];
  const float* W_edge  = (const float*)d_in[5];
  const float* b_edge  = (const float*)d_in[6];
  const float* att_W1  = (const float*)d_in[7];
  const float* att_W2  = (const float*)d_in[8];
  const float* att_v   = (const float*)d_in[9];
  const float* obs_Wi  = (const float*)d_in[10];
  const float* obs_Wh  = (const float*)d_in[11];
  const float* obs_b   = (const float*)d_in[12];
  const float* st_Wi   = (const float*)d_in[13];
  const float* st_Wh   = (const float*)d_in[14];
  const float* st_b    = (const float*)d_in[15];
  const float* oh0_W   = (const float*)d_in[16];
  const float* oh0_b   = (const float*)d_in[17];
  const float* oc0_W   = (const float*)d_in[18];
  const float* oc0_b   = (const float*)d_in[19];
  const float* sh0_W   = (const float*)d_in[20];
  const float* sh0_b   = (const float*)d_in[21];
  const float* sc0_W   = (const float*)d_in[22];
  const float* sc0_b   = (const float*)d_in[23];
  const float* act_W1  = (const float*)d_in[24];
  const float* act_b1  = (const float*)d_in[25];
  const float* act_W2  = (const float*)d_in[26];
  const float* act_b2  = (const float*)d_in[27];
  const float* dyn_A   = (const float*)d_in[28];
  const float* dyn_B   = (const float*)d_in[29];

  const float* s0 = state_history + 3*N_NODES*SD;

  float* wsf = (float*)d_ws;
  float* sbuf0 = wsf;
  float* sbuf1 = sbuf0 + N_NODES*SD;
  float* oh  = sbuf1 + N_NODES*SD;
  float* oc  = oh + N_NODES*HH;
  float* sh  = oc + N_NODES*HH;
  float* sc  = sh + N_NODES*HH;
  float* u   = sc + N_NODES*HH;
  float* ctx = u  + N_NODES*ID;
  float* sbuf[2] = { sbuf0, sbuf1 };

  // packed bf16 weights after the fp32 state region (5,940,000 floats = 23.76 MB)
  unsigned int* wp_obs = (unsigned int*)(ctx + N_NODES*ED);
  unsigned int* wp_st  = wp_obs + 49152;
  unsigned int* wp_act = wp_st  + 40960;

  float* out_state = (float*)d_out;
  float* out_input = out_state + FT*N_NODES*SD;

  hipLaunchKernelGGL(pack_weights, dim3(432), dim3(256), 0, stream,
      obs_Wi, obs_Wh, st_Wi, st_Wh, act_W1, wp_obs, wp_st, wp_act);

  hipLaunchKernelGGL(init_kernel, dim3((N_NODES*HH+255)/256), dim3(256), 0, stream,
      s0, oh0_W, oh0_b, oc0_W, oc0_b, sh0_W, sh0_b, sc0_W, sc0_b, oh, oc, sh, sc, u);

  for (int t = 0; t < FT; ++t){
    const float* s_prev = (t==0) ? s0 : sbuf[(t-1)&1];
    float* s_next = sbuf[t&1];
    hipLaunchKernelGGL(edge_att, dim3(N_NODES/4), dim3(256), 0, stream,
        s_prev, s0, edge_idx1, edge_idx2, node_obs_idx,
        W_edge, b_edge, att_W1, att_W2, att_v, ctx);
    hipLaunchKernelGGL(node_update_mfma, dim3(N_NODES/NT), dim3(256), 0, stream,
        s_prev, s0, z, ctx,
        wp_obs, wp_st, wp_act,
        obs_b, st_b, act_b1, act_W2, act_b2, dyn_A, dyn_B,
        oh, oc, sh, sc, u, s_next, out_state, out_input, t);
  }
}

// Round 8
// 406.294 us; speedup vs baseline: 3.1335x; 1.7691x over previous
//
#include <hip/hip_runtime.h>
#include <hip/hip_bf16.h>
#include <math.h>

#define N_NODES 10000
#define KE 31
#define SD 8
#define ID 2
#define ZD 32
#define ED 64
#define HH 128
#define FC 128
#define AT 16
#define FT 6
#define DT_C 0.25f
#define NT 16          // nodes per node_update block: grid = 625 exactly
#define NB 4           // nodes per edge_att block: 124 edges -> M=128, grid = 2500

#define NKS_O 6        // obs LSTM K=192 = 6*32
#define NKS_S 5        // st LSTM  K=160 = 5*32
#define NKS_A 10       // act1     K=320 = 10*32

// packed-weight sizes (uints)
#define WP_OBS_SZ 49152
#define WP_ST_SZ  40960
#define WP_ACT_SZ 20480
#define WP_EDGE_SZ 1024   // W_edge: 4 ctiles x 1 ks x 256
#define WP_ATT1_SZ 512    // att_W1: 1 ctile x 2 ks x 256

typedef __bf16 bf16x8 __attribute__((ext_vector_type(8)));
typedef float  f32x4  __attribute__((ext_vector_type(4)));

__device__ __forceinline__ float sigm(float x){ return 1.0f/(1.0f+__expf(-x)); }
__device__ __forceinline__ float tanh_f(float x){ return 1.0f - 2.0f/(1.0f+__expf(2.0f*x)); }

__device__ __forceinline__ unsigned short f2b(float f){
  __hip_bfloat16 h = __float2bfloat16(f);
  return __builtin_bit_cast(unsigned short, h);
}
__device__ __forceinline__ unsigned int pack2(float a, float b){
  return (unsigned int)f2b(a) | ((unsigned int)f2b(b) << 16);
}
__device__ __forceinline__ bf16x8 as_bf16x8(int4 v){
  union { int4 i; bf16x8 b; } u; u.i = v; return u.b;
}
// swizzled halfword index into a [rows][64] bf16 LDS tile (row stride 128B)
__device__ __forceinline__ int hwaddr(int e, int d){
  return e*64 + ((((d>>3)<<3) ^ ((e&7)<<3)) + (d&7));
}

// ---------------- pack_weights: fp32 W -> bf16 B-fragment order in ws ----------------
// B-frag map (16x16x32): col = ctile*16 + (lane&15); k = ks*32 + (lane>>4)*8 + j
__global__ __launch_bounds__(256) void pack_weights(
    const float* __restrict__ obs_Wi, const float* __restrict__ obs_Wh,
    const float* __restrict__ st_Wi,  const float* __restrict__ st_Wh,
    const float* __restrict__ act_W1, const float* __restrict__ W_edge,
    const float* __restrict__ att_W1,
    unsigned int* __restrict__ wp_obs, unsigned int* __restrict__ wp_st,
    unsigned int* __restrict__ wp_act, unsigned int* __restrict__ wp_edge,
    unsigned int* __restrict__ wp_att1)
{
  int t = blockIdx.x*256 + threadIdx.x;
  if (t < 49152){                       // obs: 32 ctiles * 6 ks * 256 uints
    int c = t / 1536; int r = t - c*1536;
    int ks = r >> 8; int q = r & 255;
    int ln = q >> 2; int dw = q & 3;
    int k  = ks*32 + ((ln>>4)<<3) + dw*2;
    int col = (c<<4) + (ln & 15);
    float v0 = (k   < 64) ? obs_Wi[k*4*HH + col]      : obs_Wh[(k-64)*4*HH + col];
    float v1 = (k+1 < 64) ? obs_Wi[(k+1)*4*HH + col]  : obs_Wh[(k-63)*4*HH + col];
    wp_obs[t] = pack2(v0, v1);
  } else if (t < 90112){                // st: 32 ctiles * 5 ks * 256
    int t2 = t - 49152;
    int c = t2 / 1280; int r = t2 - c*1280;
    int ks = r >> 8; int q = r & 255;
    int ln = q >> 2; int dw = q & 3;
    int k  = ks*32 + ((ln>>4)<<3) + dw*2;
    int col = (c<<4) + (ln & 15);
    float v0, v1;
    { int kk=k;   v0 = (kk<10)? st_Wi[kk*4*HH+col] : (kk<138 ? st_Wh[(kk-10)*4*HH+col] : 0.f); }
    { int kk=k+1; v1 = (kk<10)? st_Wi[kk*4*HH+col] : (kk<138 ? st_Wh[(kk-10)*4*HH+col] : 0.f); }
    wp_st[t2] = pack2(v0, v1);
  } else if (t < 110592){               // act1: 8 ctiles * 10 ks * 256
    int t3 = t - 90112;
    int c = t3 / 2560; int r = t3 - c*2560;
    int ks = r >> 8; int q = r & 255;
    int ln = q >> 2; int dw = q & 3;
    int k  = ks*32 + ((ln>>4)<<3) + dw*2;
    int col = (c<<4) + (ln & 15);
    float v0 = (k   < 296) ? act_W1[k*FC + col]     : 0.f;
    float v1 = (k+1 < 296) ? act_W1[(k+1)*FC + col] : 0.f;
    wp_act[t3] = pack2(v0, v1);
  } else if (t < 111616){               // W_edge: 4 ctiles * 1 ks * 256 (K=16 real, pad 32)
    int t4 = t - 110592;
    int c = t4 >> 8; int r = t4 & 255;
    int ln = r >> 2; int dw = r & 3;
    int k  = ((ln>>4)<<3) + dw*2;
    int col = (c<<4) + (ln & 15);
    float v0 = (k   < 16) ? W_edge[k*ED + col]     : 0.f;
    float v1 = (k+1 < 16) ? W_edge[(k+1)*ED + col] : 0.f;
    wp_edge[t4] = pack2(v0, v1);
  } else if (t < 112128){               // att_W1: 1 ctile * 2 ks * 256 (K=64)
    int t5 = t - 111616;
    int ks = t5 >> 8; int r = t5 & 255;
    int ln = r >> 2; int dw = r & 3;
    int k  = ks*32 + ((ln>>4)<<3) + dw*2;
    int col = ln & 15;
    float v0 = (k   < 64) ? att_W1[k*AT + col]     : 0.f;
    float v1 = (k+1 < 64) ? att_W1[(k+1)*AT + col] : 0.f;
    wp_att1[t5] = pack2(v0, v1);
  }
}

// ---------------- init: oh/oc/sh/sc = s0 @ W + b ; u = 0 ----------------
__global__ __launch_bounds__(256) void init_kernel(
    const float* __restrict__ s0,
    const float* __restrict__ oh0_W, const float* __restrict__ oh0_b,
    const float* __restrict__ oc0_W, const float* __restrict__ oc0_b,
    const float* __restrict__ sh0_W, const float* __restrict__ sh0_b,
    const float* __restrict__ sc0_W, const float* __restrict__ sc0_b,
    float* __restrict__ oh, float* __restrict__ oc,
    float* __restrict__ sh, float* __restrict__ sc, float* __restrict__ u)
{
  int t = blockIdx.x*256 + threadIdx.x;
  if (t < N_NODES*ID) u[t] = 0.0f;
  if (t >= N_NODES*HH) return;
  int n = t >> 7, j = t & 127;
  float s[SD];
  #pragma unroll
  for (int i=0;i<SD;i++) s[i] = s0[n*SD+i];
  float a0=oh0_b[j], a1=oc0_b[j], a2=sh0_b[j], a3=sc0_b[j];
  #pragma unroll
  for (int i=0;i<SD;i++){
    a0 = fmaf(s[i], oh0_W[i*HH+j], a0);
    a1 = fmaf(s[i], oc0_W[i*HH+j], a1);
    a2 = fmaf(s[i], sh0_W[i*HH+j], a2);
    a3 = fmaf(s[i], sc0_W[i*HH+j], a3);
  }
  oh[t]=a0; oc[t]=a1; sh[t]=a2; sc[t]=a3;
}

// ---------------- K1: MFMA edge encode + attention -> ctx [N, ED] ----------------
// NB=4 nodes/block, 124 edges -> M=128 (8 M-tiles). 256 threads = 4 waves.
// Stages: 1) gather E + rel  2) enc = relu(E@W_edge+b) -> swizzled bf16 LDS
//         3) Spre = enc@att_W1, score = att_v . tanh(Spre + rel@att_W2)
//         4) per-node softmax -> alpha scattered into P A-frag
//         5) ctx = P @ enc  (MFMA, B-frag gathered from swizzled enc)
__global__ __launch_bounds__(256) void edge_att_mfma(
    const float* __restrict__ s_prev, const float* __restrict__ s0,
    const int* __restrict__ edge_idx1, const int* __restrict__ edge_idx2,
    const int* __restrict__ node_obs_idx,
    const unsigned int* __restrict__ wp_edge, const unsigned int* __restrict__ wp_att1,
    const float* __restrict__ b_edge, const float* __restrict__ att_W2,
    const float* __restrict__ att_v, float* __restrict__ ctx)
{
  __shared__ __align__(16) unsigned int eF[8*64*4];     // E A-frags (8 Mt)   8 KB
  __shared__ __align__(16) unsigned short encL[128*64]; // enc bf16 swizzled 16 KB
  __shared__ __align__(16) unsigned int pF[4*64*4];     // P A-frags (K=128)  4 KB
  __shared__ float scores[128];
  __shared__ float relbuf[NB][SD];
  __shared__ float relW2b[NB][AT];
  __shared__ unsigned char emask[128];

  const int tid  = threadIdx.x;
  const int lane = tid & 63;
  const int w    = tid >> 6;
  const int n0   = blockIdx.x * NB;
  const int EPB  = NB*KE;   // 124

  // ---- stage 1: zero P, gather E rows (2 x float4 per endpoint), rel ----
  {
    ((uint4*)pF)[tid] = (uint4){0,0,0,0};
    int eb  = tid >> 1;        // 0..127
    int khi = tid & 1;         // 0: endpoint1, 1: endpoint2
    int valid = 0;
    float4 a = (float4){0,0,0,0}, b = (float4){0,0,0,0};
    if (eb < EPB){
      int nl = eb / KE;
      int j  = eb - nl*KE;
      int idx = node_obs_idx[(n0+nl)*KE + j];
      if (idx > 0){
        valid = 1;
        int e = idx - 1;
        int i = khi ? edge_idx2[e] : edge_idx1[e];
        const float4* sp = (const float4*)(s_prev + i*SD);
        a = sp[0]; b = sp[1];
      }
    }
    int mt = eb >> 4;
    int base = ((mt<<6) + (eb&15) + (khi<<4)) << 2;
    ((uint4*)&eF[base])[0] = (uint4){pack2(a.x,a.y), pack2(a.z,a.w), pack2(b.x,b.y), pack2(b.z,b.w)};
    int zbase = ((mt<<6) + (eb&15) + ((khi+2)<<4)) << 2;
    ((uint4*)&eF[zbase])[0] = (uint4){0,0,0,0};
    if (khi == 0) emask[eb] = (unsigned char)valid;
    if (tid < NB*SD){
      int m = tid >> 3, i = tid & 7;
      relbuf[m][i] = s_prev[(n0+m)*SD + i] - s0[(n0+m)*SD + i];
    }
  }
  __syncthreads();

  // ---- stage 2: enc MFMA; relW2 on wave 0 ----
  if (tid < NB*AT){
    int m = tid >> 4, a = tid & 15;
    float acc = 0.f;
    #pragma unroll
    for (int i = 0; i < SD; ++i) acc = fmaf(relbuf[m][i], att_W2[i*AT + a], acc);
    relW2b[m][a] = acc;
  }
  {
    const int c = lane & 15, g = lane >> 4;
    #pragma unroll
    for (int q = 0; q < 2; ++q){
      int mt = w*2 + q;
      bf16x8 A = as_bf16x8(*(const int4*)&eF[((mt<<6) + lane) << 2]);
      f32x4 acc[4];
      #pragma unroll
      for (int ct = 0; ct < 4; ++ct){
        bf16x8 B = as_bf16x8(*(const int4*)&wp_edge[((ct<<6) + lane) << 2]);
        acc[ct] = (f32x4){0,0,0,0};
        acc[ct] = __builtin_amdgcn_mfma_f32_16x16x32_bf16(A, B, acc[ct], 0, 0, 0);
      }
      #pragma unroll
      for (int ct = 0; ct < 4; ++ct){
        int d = ct*16 + c;
        float bias = b_edge[d];
        #pragma unroll
        for (int r = 0; r < 4; ++r){
          int eb = mt*16 + g*4 + r;
          float v = acc[ct][r] + bias;
          v = emask[eb] ? fmaxf(v, 0.f) : 0.f;
          encL[hwaddr(eb, d)] = f2b(v);
        }
      }
    }
  }
  __syncthreads();

  // ---- stage 3: score MFMA + tanh + att_v dot + 16-lane reduce ----
  {
    const int c = lane & 15, g = lane >> 4;
    const float av = att_v[c];
    #pragma unroll
    for (int q = 0; q < 2; ++q){
      int mt = w*2 + q;
      int row = mt*16 + c;
      f32x4 acc = (f32x4){0,0,0,0};
      #pragma unroll
      for (int ks = 0; ks < 2; ++ks){
        int hw = row*64 + (((ks*4 + g) << 3) ^ ((row&7) << 3));
        bf16x8 A = *(const bf16x8*)&encL[hw];
        bf16x8 B = as_bf16x8(*(const int4*)&wp_att1[((ks<<6) + lane) << 2]);
        acc = __builtin_amdgcn_mfma_f32_16x16x32_bf16(A, B, acc, 0, 0, 0);
      }
      #pragma unroll
      for (int r = 0; r < 4; ++r){
        int eb = mt*16 + g*4 + r;
        int nm = eb / KE; if (nm > NB-1) nm = NB-1;
        float sv = av * tanh_f(acc[r] + relW2b[nm][c]);
        #pragma unroll
        for (int off = 1; off < 16; off <<= 1) sv += __shfl_xor(sv, off);
        if (c == 0 && eb < EPB) scores[eb] = sv;
      }
    }
  }
  __syncthreads();

  // ---- stage 4: softmax per node (wave w = node w) -> alpha into P A-frag ----
  {
    int m = w;
    float sc_ = (lane < KE) ? scores[m*KE + lane] : -INFINITY;
    float mx = sc_;
    #pragma unroll
    for (int off = 32; off; off >>= 1) mx = fmaxf(mx, __shfl_xor(mx, off));
    float p = (lane < KE) ? __expf(sc_ - mx) : 0.f;
    float sm = p;
    #pragma unroll
    for (int off = 32; off; off >>= 1) sm += __shfl_xor(sm, off);
    float alpha = p / sm;
    if (lane < KE){
      int k = m*KE + lane;
      int ks = k >> 5;
      int ln = m | (((k>>3)&3) << 4);
      ((unsigned short*)pF)[((ks<<6) + ln)*8 + (k&7)] = f2b(alpha);
    }
  }
  __syncthreads();

  // ---- stage 5: ctx = P @ enc (wave w = column tile w) ----
  {
    const int c = lane & 15, g = lane >> 4;
    const int d = w*16 + c;
    f32x4 acc = (f32x4){0,0,0,0};
    #pragma unroll
    for (int ks = 0; ks < 4; ++ks){
      bf16x8 A = as_bf16x8(*(const int4*)&pF[((ks<<6) + lane) << 2]);
      union { unsigned short u[8]; bf16x8 v; } bb;
      #pragma unroll
      for (int j = 0; j < 8; ++j){
        int e = ks*32 + g*8 + j;
        bb.u[j] = encL[hwaddr(e, d)];
      }
      acc = __builtin_amdgcn_mfma_f32_16x16x32_bf16(A, bb.v, acc, 0, 0, 0);
    }
    if (g == 0){
      #pragma unroll
      for (int r = 0; r < 4; ++r){
        ctx[(n0 + r)*ED + d] = acc[r];   // rows 0..3 = the NB real nodes
      }
    }
  }
}

// ---------------- K2: MFMA LSTMs + action net + dynamics (unchanged) ----------------
__global__ __launch_bounds__(256) void node_update_mfma(
    const float* __restrict__ s_prev, const float* __restrict__ s0,
    const float* __restrict__ z, const float* __restrict__ ctx,
    const unsigned int* __restrict__ wp_obs, const unsigned int* __restrict__ wp_st,
    const unsigned int* __restrict__ wp_act,
    const float* __restrict__ obs_b, const float* __restrict__ st_b,
    const float* __restrict__ act_b1,
    const float* __restrict__ act_W2, const float* __restrict__ act_b2,
    const float* __restrict__ dyn_A, const float* __restrict__ dyn_B,
    float* __restrict__ oh, float* __restrict__ oc,
    float* __restrict__ sh, float* __restrict__ sc,
    float* __restrict__ u, float* __restrict__ s_next,
    float* __restrict__ out_state, float* __restrict__ out_input, int tstep)
{
  __shared__ __align__(16) unsigned int fragX1[NKS_O*64*4];
  __shared__ __align__(16) unsigned int fragX2[NKS_S*64*4];
  __shared__ __align__(16) unsigned int fragX3[NKS_A*64*4];
  __shared__ float F[NT][FC+4];
  __shared__ float sps[NT][SD];
  __shared__ float u2p[NT][ID][8];
  __shared__ float u2s[NT][ID];

  const int tid  = threadIdx.x;
  const int n0   = blockIdx.x * NT;
  const int w    = tid >> 6;
  const int lane = tid & 63;

  for (int idx = tid; idx < 16*96; idx += 256){
    int m = idx / 96, kp = idx - m*96; int k0 = kp*2; int gn = n0 + m;
    float v0, v1;
    if (k0 < ED){ v0 = ctx[gn*ED + k0]; v1 = ctx[gn*ED + k0 + 1]; }
    else        { v0 = oh[gn*HH + k0 - ED]; v1 = oh[gn*HH + k0 - ED + 1]; }
    int ln = m | (((k0>>3)&3)<<4);
    fragX1[(((k0>>5)*64 + ln)<<2) + ((k0&7)>>1)] = pack2(v0, v1);
  }
  for (int idx = tid; idx < 16*80; idx += 256){
    int m = idx / 80, kp = idx - m*80; int k0 = kp*2; int gn = n0 + m;
    float v0, v1;
    {
      int k = k0;
      v0 = (k<8) ? (s_prev[gn*SD+k]-s0[gn*SD+k]) : (k<10 ? u[gn*ID + k-8] : (k<138 ? sh[gn*HH + k-10] : 0.f));
      k = k0+1;
      v1 = (k<8) ? (s_prev[gn*SD+k]-s0[gn*SD+k]) : (k<10 ? u[gn*ID + k-8] : (k<138 ? sh[gn*HH + k-10] : 0.f));
    }
    int ln = m | (((k0>>3)&3)<<4);
    fragX2[(((k0>>5)*64 + ln)<<2) + ((k0&7)>>1)] = pack2(v0, v1);
  }
  for (int idx = tid; idx < 16*32; idx += 256){
    int m = idx / 32, p = idx - m*32; int gn = n0 + m;
    int k0 = (p < 4) ? p*2 : 256 + p*2;
    float v0, v1;
    if (k0 < 8){ v0 = s_prev[gn*SD+k0]-s0[gn*SD+k0]; v1 = s_prev[gn*SD+k0+1]-s0[gn*SD+k0+1]; }
    else if (k0 < 296){ v0 = z[gn*ZD + k0-264]; v1 = z[gn*ZD + k0-263]; }
    else { v0 = 0.f; v1 = 0.f; }
    int ln = m | (((k0>>3)&3)<<4);
    fragX3[(((k0>>5)*64 + ln)<<2) + ((k0&7)>>1)] = pack2(v0, v1);
  }
  if (tid < NT*SD){
    int m = tid >> 3, i = tid & 7;
    sps[m][i] = s_prev[(n0+m)*SD + i];
  }
  __syncthreads();

  #pragma unroll
  for (int t = 0; t < 2; ++t){
    const int hcol = w*32 + t*16 + (lane & 15);
    f32x4 acc[4];
    #pragma unroll
    for (int g = 0; g < 4; ++g){
      float b = obs_b[g*HH + hcol];
      acc[g] = (f32x4){b, b, b, b};
    }
    for (int ks = 0; ks < NKS_O; ++ks){
      bf16x8 a = as_bf16x8(*(const int4*)&fragX1[((ks*64 + lane)<<2)]);
      #pragma unroll
      for (int g = 0; g < 4; ++g){
        int c = g*8 + w*2 + t;
        bf16x8 b = as_bf16x8(*(const int4*)&wp_obs[(((c*NKS_O + ks)*64 + lane)<<2)]);
        acc[g] = __builtin_amdgcn_mfma_f32_16x16x32_bf16(a, b, acc[g], 0, 0, 0);
      }
    }
    #pragma unroll
    for (int r = 0; r < 4; ++r){
      int m = ((lane>>4)<<2) + r; int gn = n0 + m;
      float gi = acc[0][r], gf = acc[1][r], gg = acc[2][r], go = acc[3][r];
      float cold = oc[gn*HH + hcol];
      float c2 = sigm(gf)*cold + sigm(gi)*tanh_f(gg);
      float h2 = sigm(go)*tanh_f(c2);
      oc[gn*HH + hcol] = c2;
      oh[gn*HH + hcol] = h2;
      int k = 8 + hcol;
      int ln = m | (((k>>3)&3)<<4);
      ((unsigned short*)fragX3)[(((k>>5)*64 + ln)<<3) + (k&7)] = f2b(h2);
    }
  }

  #pragma unroll
  for (int t = 0; t < 2; ++t){
    const int hcol = w*32 + t*16 + (lane & 15);
    f32x4 acc[4];
    #pragma unroll
    for (int g = 0; g < 4; ++g){
      float b = st_b[g*HH + hcol];
      acc[g] = (f32x4){b, b, b, b};
    }
    for (int ks = 0; ks < NKS_S; ++ks){
      bf16x8 a = as_bf16x8(*(const int4*)&fragX2[((ks*64 + lane)<<2)]);
      #pragma unroll
      for (int g = 0; g < 4; ++g){
        int c = g*8 + w*2 + t;
        bf16x8 b = as_bf16x8(*(const int4*)&wp_st[(((c*NKS_S + ks)*64 + lane)<<2)]);
        acc[g] = __builtin_amdgcn_mfma_f32_16x16x32_bf16(a, b, acc[g], 0, 0, 0);
      }
    }
    #pragma unroll
    for (int r = 0; r < 4; ++r){
      int m = ((lane>>4)<<2) + r; int gn = n0 + m;
      float gi = acc[0][r], gf = acc[1][r], gg = acc[2][r], go = acc[3][r];
      float cold = sc[gn*HH + hcol];
      float c2 = sigm(gf)*cold + sigm(gi)*tanh_f(gg);
      float h2 = sigm(go)*tanh_f(c2);
      sc[gn*HH + hcol] = c2;
      sh[gn*HH + hcol] = h2;
      int k = 136 + hcol;
      int ln = m | (((k>>3)&3)<<4);
      ((unsigned short*)fragX3)[(((k>>5)*64 + ln)<<3) + (k&7)] = f2b(h2);
    }
  }
  __syncthreads();

  #pragma unroll
  for (int t = 0; t < 2; ++t){
    const int col = w*32 + t*16 + (lane & 15);
    float b = act_b1[col];
    f32x4 acc = (f32x4){b, b, b, b};
    for (int ks = 0; ks < NKS_A; ++ks){
      bf16x8 a = as_bf16x8(*(const int4*)&fragX3[((ks*64 + lane)<<2)]);
      int c = w*2 + t;
      bf16x8 bb = as_bf16x8(*(const int4*)&wp_act[(((c*NKS_A + ks)*64 + lane)<<2)]);
      acc = __builtin_amdgcn_mfma_f32_16x16x32_bf16(a, bb, acc, 0, 0, 0);
    }
    #pragma unroll
    for (int r = 0; r < 4; ++r){
      int m = ((lane>>4)<<2) + r;
      F[m][col] = fmaxf(acc[r], 0.f);
    }
  }
  __syncthreads();

  {
    int m  = tid >> 4;
    int c  = (tid >> 3) & 1;
    int kq = tid & 7;
    float p = 0.f;
    #pragma unroll
    for (int i = 0; i < 16; ++i){
      int j = kq*16 + i;
      p = fmaf(F[m][j], act_W2[j*ID + c], p);
    }
    u2p[m][c][kq] = p;
  }
  __syncthreads();
  if (tid < NT*ID){
    int m = tid >> 1, c = tid & 1; int gn = n0 + m;
    float s = act_b2[c];
    #pragma unroll
    for (int kq = 0; kq < 8; ++kq) s += u2p[m][c][kq];
    u2s[m][c] = s;
    u[gn*ID + c] = s;
    out_input[tstep*N_NODES*ID + gn*ID + c] = s;
  }
  __syncthreads();

  if (tid < NT*SD){
    int m = tid >> 3, d = tid & 7; int gn = n0 + m;
    float acc = 0.f;
    #pragma unroll
    for (int e = 0; e < SD; ++e) acc = fmaf(sps[m][e], dyn_A[d*SD+e], acc);
    #pragma unroll
    for (int c = 0; c < ID; ++c) acc = fmaf(u2s[m][c], dyn_B[d*ID+c], acc);
    float s2v = sps[m][d] + DT_C*acc;
    s_next[gn*SD+d] = s2v;
    out_state[tstep*N_NODES*SD + gn*SD + d] = s2v;
  }
}

extern "C" void kernel_launch(void* const* d_in, const int* in_sizes, int n_in,
                              void* d_out, int out_size, void* d_ws, size_t ws_size,
                              hipStream_t stream)
{
  const float* state_history = (const float*)d_in[0];
  const float* z        = (const float*)d_in[1];
  const int*   edge_idx1 = (const int*)d_in[2];
  const int*   edge_idx2 = (const int*)d_in[3];
  const int*   node_obs_idx = (const int*)d_in[4];
  const float* W_edge  = (const float*)d_in[5];
  const float* b_edge  = (const float*)d_in[6];
  const float* att_W1  = (const float*)d_in[7];
  const float* att_W2  = (const float*)d_in[8];
  const float* att_v   = (const float*)d_in[9];
  const float* obs_Wi  = (const float*)d_in[10];
  const float* obs_Wh  = (const float*)d_in[11];
  const float* obs_b   = (const float*)d_in[12];
  const float* st_Wi   = (const float*)d_in[13];
  const float* st_Wh   = (const float*)d_in[14];
  const float* st_b    = (const float*)d_in[15];
  const float* oh0_W   = (const float*)d_in[16];
  const float* oh0_b   = (const float*)d_in[17];
  const float* oc0_W   = (const float*)d_in[18];
  const float* oc0_b   = (const float*)d_in[19];
  const float* sh0_W   = (const float*)d_in[20];
  const float* sh0_b   = (const float*)d_in[21];
  const float* sc0_W   = (const float*)d_in[22];
  const float* sc0_b   = (const float*)d_in[23];
  const float* act_W1  = (const float*)d_in[24];
  const float* act_b1  = (const float*)d_in[25];
  const float* act_W2  = (const float*)d_in[26];
  const float* act_b2  = (const float*)d_in[27];
  const float* dyn_A   = (const float*)d_in[28];
  const float* dyn_B   = (const float*)d_in[29];

  const float* s0 = state_history + 3*N_NODES*SD;

  float* wsf = (float*)d_ws;
  float* sbuf0 = wsf;
  float* sbuf1 = sbuf0 + N_NODES*SD;
  float* oh  = sbuf1 + N_NODES*SD;
  float* oc  = oh + N_NODES*HH;
  float* sh  = oc + N_NODES*HH;
  float* sc  = sh + N_NODES*HH;
  float* u   = sc + N_NODES*HH;
  float* ctx = u  + N_NODES*ID;
  float* sbuf[2] = { sbuf0, sbuf1 };

  unsigned int* wp_obs  = (unsigned int*)(ctx + N_NODES*ED);
  unsigned int* wp_st   = wp_obs + WP_OBS_SZ;
  unsigned int* wp_act  = wp_st  + WP_ST_SZ;
  unsigned int* wp_edge = wp_act + WP_ACT_SZ;
  unsigned int* wp_att1 = wp_edge + WP_EDGE_SZ;

  float* out_state = (float*)d_out;
  float* out_input = out_state + FT*N_NODES*SD;

  hipLaunchKernelGGL(pack_weights, dim3(438), dim3(256), 0, stream,
      obs_Wi, obs_Wh, st_Wi, st_Wh, act_W1, W_edge, att_W1,
      wp_obs, wp_st, wp_act, wp_edge, wp_att1);

  hipLaunchKernelGGL(init_kernel, dim3((N_NODES*HH+255)/256), dim3(256), 0, stream,
      s0, oh0_W, oh0_b, oc0_W, oc0_b, sh0_W, sh0_b, sc0_W, sc0_b, oh, oc, sh, sc, u);

  for (int t = 0; t < FT; ++t){
    const float* s_prev = (t==0) ? s0 : sbuf[(t-1)&1];
    float* s_next = sbuf[t&1];
    hipLaunchKernelGGL(edge_att_mfma, dim3(N_NODES/NB), dim3(256), 0, stream,
        s_prev, s0, edge_idx1, edge_idx2, node_obs_idx,
        wp_edge, wp_att1, b_edge, att_W2, att_v, ctx);
    hipLaunchKernelGGL(node_update_mfma, dim3(N_NODES/NT), dim3(256), 0, stream,
        s_prev, s0, z, ctx,
        wp_obs, wp_st, wp_act,
        obs_b, st_b, act_b1, act_W2, act_b2, dyn_A, dyn_B,
        oh, oc, sh, sc, u, s_next, out_state, out_input, t);
  }
}